// Round 1
// baseline (119.624 us; speedup 1.0000x reference)
//
#include <hip/hip_runtime.h>
#include <hip/hip_bf16.h>

typedef __bf16 bf16x8 __attribute__((ext_vector_type(8)));
typedef __bf16 bf16x4 __attribute__((ext_vector_type(4)));
typedef float  f32x4  __attribute__((ext_vector_type(4)));

#define NB  8
#define SEQ 2048
#define DM  1024
#define HD  64

// ---------------- kernel 0: W (3 x [64,1024] f32) -> packed bf16 [192][1024]
__global__ void k_convw(const float* __restrict__ Wq, const float* __restrict__ Wk,
                        const float* __restrict__ Wv, __bf16* __restrict__ Wb) {
    int idx = blockIdx.x * blockDim.x + threadIdx.x;   // 49152 threads, 4 elems each
    int e = idx * 4;
    const float* src;
    if (e < 65536)       src = Wq + e;
    else if (e < 131072) src = Wk + (e - 65536);
    else                 src = Wv + (e - 131072);
    float4 v = *reinterpret_cast<const float4*>(src);
    bf16x4 o;
    o[0] = (__bf16)v.x; o[1] = (__bf16)v.y; o[2] = (__bf16)v.z; o[3] = (__bf16)v.w;
    *reinterpret_cast<bf16x4*>(Wb + e) = o;
}

// ---------------- kernel 1: QKV projection (bf16 MFMA, fp32 accum)
// X [16384][1024] f32, Wb [192][1024] bf16 -> Qb,Kb [B][S][64] bf16, Vt [B][64][S] bf16
__launch_bounds__(256)
__global__ void k_proj(const float* __restrict__ X, const __bf16* __restrict__ Wb,
                       __bf16* __restrict__ Qb, __bf16* __restrict__ Kb,
                       __bf16* __restrict__ Vt) {
    __shared__ __align__(16) __bf16 Xs[64][72];   // +8 pad: 144B row stride
    const int tid = threadIdx.x;
    const int w = tid >> 6, l = tid & 63;
    const int lr = l & 15, lg = l >> 4;
    const int m0 = blockIdx.x * 64;

    f32x4 acc[3][4];
    #pragma unroll
    for (int i = 0; i < 3; ++i)
        #pragma unroll
        for (int j = 0; j < 4; ++j)
            acc[i][j] = f32x4{0.f, 0.f, 0.f, 0.f};

    for (int kb = 0; kb < DM; kb += 64) {
        // stage 64x64 f32 -> bf16 LDS tile
        #pragma unroll
        for (int i = 0; i < 4; ++i) {
            int u = tid + 256 * i;
            int row = u >> 4, c4 = (u & 15) * 4;
            float4 v = *reinterpret_cast<const float4*>(X + (size_t)(m0 + row) * DM + kb + c4);
            bf16x4 o;
            o[0] = (__bf16)v.x; o[1] = (__bf16)v.y; o[2] = (__bf16)v.z; o[3] = (__bf16)v.w;
            *reinterpret_cast<bf16x4*>(&Xs[row][c4]) = o;
        }
        __syncthreads();
        #pragma unroll
        for (int ks = 0; ks < 64; ks += 32) {
            bf16x8 a[4];
            #pragma unroll
            for (int rt = 0; rt < 4; ++rt)
                a[rt] = *reinterpret_cast<const bf16x8*>(&Xs[16 * rt + lr][ks + lg * 8]);
            #pragma unroll
            for (int mtx = 0; mtx < 3; ++mtx) {
                bf16x8 bfr = *reinterpret_cast<const bf16x8*>(
                    Wb + (size_t)(mtx * 64 + 16 * w + lr) * DM + kb + ks + lg * 8);
                #pragma unroll
                for (int rt = 0; rt < 4; ++rt)
                    acc[mtx][rt] = __builtin_amdgcn_mfma_f32_16x16x32_bf16(
                        a[rt], bfr, acc[mtx][rt], 0, 0, 0);
            }
        }
        __syncthreads();
    }

    const int d = 16 * w + lr;
    #pragma unroll
    for (int rt = 0; rt < 4; ++rt) {
        int rowbase = m0 + 16 * rt + lg * 4;   // 4 consecutive rows: regs r=0..3
        #pragma unroll
        for (int r = 0; r < 4; ++r) {
            size_t off = (size_t)(rowbase + r) * HD + d;
            Qb[off] = (__bf16)acc[0][rt][r];
            Kb[off] = (__bf16)acc[1][rt][r];
        }
        // V stored transposed: Vt[b][d][s], 4 consecutive s -> packed 8B store
        int bb = rowbase >> 11;
        int s0 = rowbase & 2047;
        bf16x4 vv;
        #pragma unroll
        for (int r = 0; r < 4; ++r) vv[r] = (__bf16)acc[2][rt][r];
        *reinterpret_cast<bf16x4*>(Vt + ((size_t)bb * HD + d) * SEQ + s0) = vv;
    }
}

// ---------------- kernel 2: causal flash attention
// Qb,Kb [B][S][64] bf16, Vt [B][64][S] bf16 -> Out [B][S][64] f32
__launch_bounds__(256)
__global__ void k_attn(const __bf16* __restrict__ Qb, const __bf16* __restrict__ Kb,
                       const __bf16* __restrict__ Vt, float* __restrict__ Out) {
    __shared__ __align__(16) __bf16 Qs[64][72];
    __shared__ __align__(16) __bf16 Ks[64][72];
    __shared__ __align__(16) __bf16 Vs[64][72];   // [d][key]
    __shared__ __align__(16) __bf16 Ps[64][72];
    const int tid = threadIdx.x;
    const int w = tid >> 6, l = tid & 63;
    const int lr = l & 15, lg = l >> 4;
    const int b = blockIdx.x >> 5, qt = blockIdx.x & 31;
    const int q0 = qt * 64;
    const __bf16* Qp = Qb + (size_t)b * SEQ * HD;
    const __bf16* Kp = Kb + (size_t)b * SEQ * HD;
    const __bf16* Vp = Vt + (size_t)b * HD * SEQ;

    // stage Q tile once
    #pragma unroll
    for (int i = 0; i < 2; ++i) {
        int u = tid + 256 * i;
        int row = u >> 3, c8 = (u & 7) * 8;
        *reinterpret_cast<bf16x8*>(&Qs[row][c8]) =
            *reinterpret_cast<const bf16x8*>(Qp + (size_t)(q0 + row) * HD + c8);
    }

    f32x4 oacc[4];
    float mrow[4], lrow[4];
    #pragma unroll
    for (int r = 0; r < 4; ++r) {
        oacc[r] = f32x4{0.f, 0.f, 0.f, 0.f};
        mrow[r] = -1e30f;
        lrow[r] = 0.f;
    }

    for (int kt = 0; kt <= qt; ++kt) {
        const int k0 = kt * 64;
        __syncthreads();   // previous iter's LDS reads done (also covers Q staging)
        #pragma unroll
        for (int i = 0; i < 2; ++i) {
            int u = tid + 256 * i;
            int row = u >> 3, c8 = (u & 7) * 8;
            *reinterpret_cast<bf16x8*>(&Ks[row][c8]) =
                *reinterpret_cast<const bf16x8*>(Kp + (size_t)(k0 + row) * HD + c8);
            *reinterpret_cast<bf16x8*>(&Vs[row][c8]) =
                *reinterpret_cast<const bf16x8*>(Vp + (size_t)row * SEQ + k0 + c8);
        }
        __syncthreads();

        // S = Q K^T  (wave w owns q-rows 16w..16w+15)
        f32x4 sacc[4];
        #pragma unroll
        for (int t = 0; t < 4; ++t) sacc[t] = f32x4{0.f, 0.f, 0.f, 0.f};
        #pragma unroll
        for (int ks = 0; ks < 2; ++ks) {
            bf16x8 a = *reinterpret_cast<const bf16x8*>(&Qs[16 * w + lr][ks * 32 + lg * 8]);
            #pragma unroll
            for (int t = 0; t < 4; ++t) {
                bf16x8 bb = *reinterpret_cast<const bf16x8*>(&Ks[16 * t + lr][ks * 32 + lg * 8]);
                sacc[t] = __builtin_amdgcn_mfma_f32_16x16x32_bf16(a, bb, sacc[t], 0, 0, 0);
            }
        }

        const bool diag = (kt == qt);
        #pragma unroll
        for (int r = 0; r < 4; ++r) {
            float mx = -1e30f;
            #pragma unroll
            for (int t = 0; t < 4; ++t) {
                float v = sacc[t][r] * 0.125f;
                if (diag && (16 * t + lr) > (16 * w + lg * 4 + r)) v = -1e30f;
                sacc[t][r] = v;
                mx = fmaxf(mx, v);
            }
            mx = fmaxf(mx, __shfl_xor(mx, 1));
            mx = fmaxf(mx, __shfl_xor(mx, 2));
            mx = fmaxf(mx, __shfl_xor(mx, 4));
            mx = fmaxf(mx, __shfl_xor(mx, 8));
            float mnew = fmaxf(mrow[r], mx);
            float fsc = __expf(mrow[r] - mnew);
            mrow[r] = mnew;
            float rs = 0.f;
            #pragma unroll
            for (int t = 0; t < 4; ++t) {
                float p = __expf(sacc[t][r] - mnew);
                sacc[t][r] = p;
                rs += p;
            }
            rs += __shfl_xor(rs, 1);
            rs += __shfl_xor(rs, 2);
            rs += __shfl_xor(rs, 4);
            rs += __shfl_xor(rs, 8);
            lrow[r] = lrow[r] * fsc + rs;
            #pragma unroll
            for (int t = 0; t < 4; ++t) oacc[t][r] *= fsc;
        }

        // P -> LDS (wave-private rows, no barrier needed)
        #pragma unroll
        for (int t = 0; t < 4; ++t)
            #pragma unroll
            for (int r = 0; r < 4; ++r)
                Ps[16 * w + lg * 4 + r][16 * t + lr] = (__bf16)sacc[t][r];

        // O += P V
        #pragma unroll
        for (int ks = 0; ks < 2; ++ks) {
            bf16x8 pa = *reinterpret_cast<const bf16x8*>(&Ps[16 * w + lr][ks * 32 + lg * 8]);
            #pragma unroll
            for (int t2 = 0; t2 < 4; ++t2) {
                bf16x8 vb = *reinterpret_cast<const bf16x8*>(&Vs[16 * t2 + lr][ks * 32 + lg * 8]);
                oacc[t2] = __builtin_amdgcn_mfma_f32_16x16x32_bf16(pa, vb, oacc[t2], 0, 0, 0);
            }
        }
    }

    float* Op = Out + ((size_t)b * SEQ + q0) * HD;
    #pragma unroll
    for (int t2 = 0; t2 < 4; ++t2)
        #pragma unroll
        for (int r = 0; r < 4; ++r)
            Op[(size_t)(16 * w + lg * 4 + r) * HD + 16 * t2 + lr] = oacc[t2][r] / lrow[r];
}

extern "C" void kernel_launch(void* const* d_in, const int* in_sizes, int n_in,
                              void* d_out, int out_size, void* d_ws, size_t ws_size,
                              hipStream_t stream) {
    const float* x  = (const float*)d_in[0];
    const float* wq = (const float*)d_in[1];
    const float* wk = (const float*)d_in[2];
    const float* wv = (const float*)d_in[3];
    char* ws = (char*)d_ws;
    __bf16* Wb = (__bf16*)ws;                                  // 384 KiB
    __bf16* Qb = (__bf16*)(ws + 524288);                       // 2 MiB
    __bf16* Kb = (__bf16*)(ws + 524288 + 2097152);             // 2 MiB
    __bf16* Vt = (__bf16*)(ws + 524288 + 2 * 2097152);         // 2 MiB
    float* out = (float*)d_out;

    hipLaunchKernelGGL(k_convw, dim3(192), dim3(256), 0, stream, wq, wk, wv, Wb);
    hipLaunchKernelGGL(k_proj,  dim3(256), dim3(256), 0, stream, x, Wb, Qb, Kb, Vt);
    hipLaunchKernelGGL(k_attn,  dim3(256), dim3(256), 0, stream, Qb, Kb, Vt, out);
}

// Round 2
// 81.454 us; speedup vs baseline: 1.4686x; 1.4686x over previous
//
#include <hip/hip_runtime.h>
#include <hip/hip_bf16.h>

typedef __bf16 bf16x8 __attribute__((ext_vector_type(8)));
typedef __bf16 bf16x4 __attribute__((ext_vector_type(4)));
typedef float  f32x4  __attribute__((ext_vector_type(4)));

#define NB  8
#define SEQ 2048
#define DM  1024
#define HD  64

// ---------------- kernel 0: W (3 x [64,1024] f32) -> packed bf16 [192][1024]
__global__ void k_convw(const float* __restrict__ Wq, const float* __restrict__ Wk,
                        const float* __restrict__ Wv, __bf16* __restrict__ Wb) {
    int idx = blockIdx.x * blockDim.x + threadIdx.x;
    int e = idx * 4;
    const float* src;
    if (e < 65536)       src = Wq + e;
    else if (e < 131072) src = Wk + (e - 65536);
    else                 src = Wv + (e - 131072);
    float4 v = *reinterpret_cast<const float4*>(src);
    bf16x4 o;
    o[0] = (__bf16)v.x; o[1] = (__bf16)v.y; o[2] = (__bf16)v.z; o[3] = (__bf16)v.w;
    *reinterpret_cast<bf16x4*>(Wb + e) = o;
}

// ---------------- kernel 1: QKV projection, M-tile=32 -> 512 blocks
// X [16384][1024] f32, Wb [192][1024] bf16 -> Qb(prescaled),Kb [B][S][64], Vt [B][64][S]
__launch_bounds__(256)
__global__ void k_proj(const float* __restrict__ X, const __bf16* __restrict__ Wb,
                       __bf16* __restrict__ Qb, __bf16* __restrict__ Kb,
                       __bf16* __restrict__ Vt) {
    __shared__ __align__(16) __bf16 Xs[32][72];
    const int tid = threadIdx.x;
    const int w = tid >> 6, l = tid & 63;
    const int lr = l & 15, lg = l >> 4;
    const int m0 = blockIdx.x * 32;

    f32x4 acc[3][2];
    #pragma unroll
    for (int i = 0; i < 3; ++i)
        #pragma unroll
        for (int j = 0; j < 2; ++j)
            acc[i][j] = f32x4{0.f, 0.f, 0.f, 0.f};

    for (int kb = 0; kb < DM; kb += 64) {
        #pragma unroll
        for (int i = 0; i < 2; ++i) {
            int u = tid + 256 * i;
            int row = u >> 4, c4 = (u & 15) * 4;
            float4 v = *reinterpret_cast<const float4*>(X + (size_t)(m0 + row) * DM + kb + c4);
            bf16x4 o;
            o[0] = (__bf16)v.x; o[1] = (__bf16)v.y; o[2] = (__bf16)v.z; o[3] = (__bf16)v.w;
            *reinterpret_cast<bf16x4*>(&Xs[row][c4]) = o;
        }
        __syncthreads();
        #pragma unroll
        for (int ks = 0; ks < 64; ks += 32) {
            bf16x8 a[2];
            #pragma unroll
            for (int rt = 0; rt < 2; ++rt)
                a[rt] = *reinterpret_cast<const bf16x8*>(&Xs[16 * rt + lr][ks + lg * 8]);
            #pragma unroll
            for (int mtx = 0; mtx < 3; ++mtx) {
                bf16x8 bfr = *reinterpret_cast<const bf16x8*>(
                    Wb + (size_t)(mtx * 64 + 16 * w + lr) * DM + kb + ks + lg * 8);
                #pragma unroll
                for (int rt = 0; rt < 2; ++rt)
                    acc[mtx][rt] = __builtin_amdgcn_mfma_f32_16x16x32_bf16(
                        a[rt], bfr, acc[mtx][rt], 0, 0, 0);
            }
        }
        __syncthreads();
    }

    const int d = 16 * w + lr;
    #pragma unroll
    for (int rt = 0; rt < 2; ++rt) {
        int rowbase = m0 + 16 * rt + lg * 4;
        #pragma unroll
        for (int r = 0; r < 4; ++r) {
            size_t off = (size_t)(rowbase + r) * HD + d;
            Qb[off] = (__bf16)(acc[0][rt][r] * 0.125f);  // pre-scale by 1/sqrt(64)
            Kb[off] = (__bf16)acc[1][rt][r];
        }
        int bb = rowbase >> 11;
        int s0 = rowbase & 2047;
        bf16x4 vv;
        #pragma unroll
        for (int r = 0; r < 4; ++r) vv[r] = (__bf16)acc[2][rt][r];
        *reinterpret_cast<bf16x4*>(Vt + ((size_t)bb * HD + d) * SEQ + s0) = vv;
    }
}

// ---------------- kernel 2: chunked causal flash attention (split-K)
// block = (b, qt, c): processes k-tiles [c*T, min(c*T+T, qt+1)) for 64 q-rows.
// Writes unnormalized partial O (bf16) + per-row m,l to workspace.
__launch_bounds__(256)
__global__ void k_attn(const __bf16* __restrict__ Qb, const __bf16* __restrict__ Kb,
                       const __bf16* __restrict__ Vt, __bf16* __restrict__ Opart,
                       float* __restrict__ ML, int T, int NC) {
    const int bid = blockIdx.x;
    const int b = bid / (32 * NC);
    const int rem = bid - b * 32 * NC;
    const int qt = rem / NC;
    const int c = rem - qt * NC;
    if (c * T > qt) return;               // inactive chunk
    const int kt0 = c * T;
    const int nt = min(T, qt + 1 - kt0);
    const int q0 = qt * 64;

    __shared__ __align__(16) __bf16 Ks[64][72];
    __shared__ __align__(16) __bf16 Vs[64][72];   // [d][key]
    __shared__ __align__(16) __bf16 Ps[64][72];
    const int tid = threadIdx.x;
    const int w = tid >> 6, l = tid & 63;
    const int lr = l & 15, lg = l >> 4;
    const __bf16* Qp = Qb + (size_t)b * SEQ * HD;
    const __bf16* Kp = Kb + (size_t)b * SEQ * HD;
    const __bf16* Vp = Vt + (size_t)b * HD * SEQ;

    // Q fragments straight to registers (wave-private rows, reused all chunk)
    bf16x8 qa[2];
    #pragma unroll
    for (int ks = 0; ks < 2; ++ks)
        qa[ks] = *reinterpret_cast<const bf16x8*>(
            Qp + (size_t)(q0 + 16 * w + lr) * HD + ks * 32 + lg * 8);

    f32x4 oacc[4];
    float mrow[4], lrow[4];
    #pragma unroll
    for (int r = 0; r < 4; ++r) {
        oacc[r] = f32x4{0.f, 0.f, 0.f, 0.f};
        mrow[r] = -1e30f;
        lrow[r] = 0.f;
    }

    for (int it = 0; it < nt; ++it) {
        const int kt = kt0 + it;
        const int k0 = kt * 64;
        __syncthreads();   // protect LDS from previous iteration's readers
        #pragma unroll
        for (int i = 0; i < 2; ++i) {
            int u = tid + 256 * i;
            int row = u >> 3, c8 = (u & 7) * 8;
            *reinterpret_cast<bf16x8*>(&Ks[row][c8]) =
                *reinterpret_cast<const bf16x8*>(Kp + (size_t)(k0 + row) * HD + c8);
            *reinterpret_cast<bf16x8*>(&Vs[row][c8]) =
                *reinterpret_cast<const bf16x8*>(Vp + (size_t)row * SEQ + k0 + c8);
        }
        __syncthreads();

        f32x4 sacc[4];
        #pragma unroll
        for (int t = 0; t < 4; ++t) sacc[t] = f32x4{0.f, 0.f, 0.f, 0.f};
        #pragma unroll
        for (int ks = 0; ks < 2; ++ks) {
            #pragma unroll
            for (int t = 0; t < 4; ++t) {
                bf16x8 bb = *reinterpret_cast<const bf16x8*>(&Ks[16 * t + lr][ks * 32 + lg * 8]);
                sacc[t] = __builtin_amdgcn_mfma_f32_16x16x32_bf16(qa[ks], bb, sacc[t], 0, 0, 0);
            }
        }

        const bool diag = (kt == qt);
        #pragma unroll
        for (int r = 0; r < 4; ++r) {
            float mx = -1e30f;
            #pragma unroll
            for (int t = 0; t < 4; ++t) {
                float v = sacc[t][r];
                if (diag && (16 * t + lr) > (16 * w + lg * 4 + r)) v = -1e30f;
                sacc[t][r] = v;
                mx = fmaxf(mx, v);
            }
            mx = fmaxf(mx, __shfl_xor(mx, 1));
            mx = fmaxf(mx, __shfl_xor(mx, 2));
            mx = fmaxf(mx, __shfl_xor(mx, 4));
            mx = fmaxf(mx, __shfl_xor(mx, 8));
            float mnew = fmaxf(mrow[r], mx);
            float fsc = __expf(mrow[r] - mnew);
            mrow[r] = mnew;
            float rs = 0.f;
            #pragma unroll
            for (int t = 0; t < 4; ++t) {
                float p = __expf(sacc[t][r] - mnew);
                sacc[t][r] = p;
                rs += p;
            }
            rs += __shfl_xor(rs, 1);
            rs += __shfl_xor(rs, 2);
            rs += __shfl_xor(rs, 4);
            rs += __shfl_xor(rs, 8);
            lrow[r] = lrow[r] * fsc + rs;
            #pragma unroll
            for (int t = 0; t < 4; ++t) oacc[t][r] *= fsc;
        }

        #pragma unroll
        for (int t = 0; t < 4; ++t)
            #pragma unroll
            for (int r = 0; r < 4; ++r)
                Ps[16 * w + lg * 4 + r][16 * t + lr] = (__bf16)sacc[t][r];

        #pragma unroll
        for (int ks = 0; ks < 2; ++ks) {
            bf16x8 pa = *reinterpret_cast<const bf16x8*>(&Ps[16 * w + lr][ks * 32 + lg * 8]);
            #pragma unroll
            for (int t2 = 0; t2 < 4; ++t2) {
                bf16x8 vb = *reinterpret_cast<const bf16x8*>(&Vs[16 * t2 + lr][ks * 32 + lg * 8]);
                oacc[t2] = __builtin_amdgcn_mfma_f32_16x16x32_bf16(pa, vb, oacc[t2], 0, 0, 0);
            }
        }
    }

    // write partials: slot = bid (grid is exactly (b,qt,c) flattened)
    const size_t slot = (size_t)bid;
    __bf16* op = Opart + slot * 4096;
    #pragma unroll
    for (int t2 = 0; t2 < 4; ++t2)
        #pragma unroll
        for (int r = 0; r < 4; ++r)
            op[(16 * w + lg * 4 + r) * 64 + 16 * t2 + lr] = (__bf16)oacc[t2][r];
    if (lr == 0) {
        float* ml = ML + slot * 128;
        #pragma unroll
        for (int r = 0; r < 4; ++r) {
            int row = 16 * w + lg * 4 + r;
            ml[row * 2]     = mrow[r];
            ml[row * 2 + 1] = lrow[r];
        }
    }
}

// ---------------- kernel 3: merge partial chunks -> Out [B][S][64] f32
__launch_bounds__(256)
__global__ void k_merge(const __bf16* __restrict__ Opart, const float* __restrict__ ML,
                        float* __restrict__ Out, int T, int NC) {
    const int bq = blockIdx.x;           // b*32 + qt
    const int qt = bq & 31;
    const int nc = qt / T + 1;           // active chunks
    const int row = threadIdx.x >> 2;
    const int cg = (threadIdx.x & 3) * 16;
    const int base = bq * NC;

    float M = -1e30f;
    for (int c = 0; c < nc; ++c)
        M = fmaxf(M, ML[(size_t)(base + c) * 128 + row * 2]);

    float L = 0.f;
    f32x4 a0{0,0,0,0}, a1{0,0,0,0}, a2{0,0,0,0}, a3{0,0,0,0};
    for (int c = 0; c < nc; ++c) {
        const float* ml = ML + (size_t)(base + c) * 128 + row * 2;
        float wgt = __expf(ml[0] - M);
        L += ml[1] * wgt;
        const __bf16* op = Opart + (size_t)(base + c) * 4096 + row * 64 + cg;
        bf16x8 v0 = *reinterpret_cast<const bf16x8*>(op);
        bf16x8 v1 = *reinterpret_cast<const bf16x8*>(op + 8);
        #pragma unroll
        for (int j = 0; j < 4; ++j) {
            a0[j] += wgt * (float)v0[j];
            a1[j] += wgt * (float)v0[4 + j];
            a2[j] += wgt * (float)v1[j];
            a3[j] += wgt * (float)v1[4 + j];
        }
    }
    float inv = 1.f / L;
    #pragma unroll
    for (int j = 0; j < 4; ++j) { a0[j] *= inv; a1[j] *= inv; a2[j] *= inv; a3[j] *= inv; }
    float* o = Out + ((size_t)bq * 64 + row) * 64 + cg;
    *reinterpret_cast<f32x4*>(o)      = a0;
    *reinterpret_cast<f32x4*>(o + 4)  = a1;
    *reinterpret_cast<f32x4*>(o + 8)  = a2;
    *reinterpret_cast<f32x4*>(o + 12) = a3;
}

extern "C" void kernel_launch(void* const* d_in, const int* in_sizes, int n_in,
                              void* d_out, int out_size, void* d_ws, size_t ws_size,
                              hipStream_t stream) {
    const float* x  = (const float*)d_in[0];
    const float* wq = (const float*)d_in[1];
    const float* wk = (const float*)d_in[2];
    const float* wv = (const float*)d_in[3];
    char* ws = (char*)d_ws;
    __bf16* Wb = (__bf16*)ws;                                  // 384 KiB (pad 512K)
    __bf16* Qb = (__bf16*)(ws + 524288);                       // 2 MiB
    __bf16* Kb = (__bf16*)(ws + 524288 + 2097152);             // 2 MiB
    __bf16* Vt = (__bf16*)(ws + 524288 + 2 * 2097152);         // 2 MiB
    const size_t base = 524288 + 3 * 2097152;                  // 6,815,744
    float* out = (float*)d_out;

    // pick chunk size T by available scratch: slots = 8*32*(32/T), 8704 B/slot
    int T;
    if (ws_size >= base + (size_t)2048 * 8704)      T = 4;
    else if (ws_size >= base + (size_t)1024 * 8704) T = 8;
    else                                            T = 32;
    const int NC = 32 / T;
    const int slots = 8 * 32 * NC;
    float*  ML    = (float*)(ws + base);
    __bf16* Opart = (__bf16*)(ws + base + (size_t)slots * 512);

    hipLaunchKernelGGL(k_convw, dim3(192), dim3(256), 0, stream, wq, wk, wv, Wb);
    hipLaunchKernelGGL(k_proj,  dim3(512), dim3(256), 0, stream, x, Wb, Qb, Kb, Vt);
    hipLaunchKernelGGL(k_attn,  dim3(8 * 32 * NC), dim3(256), 0, stream,
                       Qb, Kb, Vt, Opart, ML, T, NC);
    hipLaunchKernelGGL(k_merge, dim3(256), dim3(256), 0, stream, Opart, ML, out, T, NC);
}